// Round 5
// baseline (442.702 us; speedup 1.0000x reference)
//
#include <hip/hip_runtime.h>
#include <cstdint>
#include <cmath>

// GPT-2 block: B=8, S=1024, D=1024, H=16, Hd=64.
// LN1 -> qkv GEMM -> MFMA flash attention -> proj GEMM(+res) -> LN2
//     -> fc GEMM(+fast GELU) -> proj2 GEMM(+res) -> out (fp32)
//
// gemm3b: BM=128, BK=32, 3 rotating LDS buffers (24/16 KB each -> 72/48 KB
//   total -> 2 blocks/CU), counted-vmcnt pipeline. Stage tile t+2 while
//   reading tile t (lead 2 < 3 buffers -> WAR-safe); uniform L loads/tile ->
//   one s_waitcnt vmcnt(L) per tile; never vmcnt(0). Two async blocks per CU
//   (4 waves/SIMD) hide lgkm/vmcnt/barrier stalls under the other block's
//   MFMA (r4 post-mortem: 1 block/CU lockstep left ~900 cyc/phase unhidden).
//   A: chunk-XOR swizzle c^((row>>1)&3) on global source (linear gl2lds
//      dest); same XOR on reads -> 0 conflicts (r4-verified).
//   B: pre-packed fragment-major -> linear LDS copy, lane-major reads.

#define Bb 8
#define Ss 1024
#define Dd 1024
#define Hh 16
#define HD 64
#define MTOK 8192  // B*S

typedef __attribute__((ext_vector_type(4))) float  floatx4;
typedef __attribute__((ext_vector_type(8))) short  short8;
typedef __attribute__((ext_vector_type(4))) short  short4v;

__device__ __forceinline__ float bf2f(unsigned short u) {
    return __uint_as_float(((unsigned int)u) << 16);
}
__device__ __forceinline__ unsigned short f2bf(float f) {
    unsigned int u = __float_as_uint(f);
    u += 0x7FFFu + ((u >> 16) & 1u);   // RNE
    return (unsigned short)(u >> 16);
}

__device__ __forceinline__ void gl2lds16(const void* g, void* l) {
    __builtin_amdgcn_global_load_lds(
        (__attribute__((address_space(1))) void*)(g),
        (__attribute__((address_space(3))) void*)(l),
        16, 0, 0);
}

template <int N> __device__ __forceinline__ void wait_vmcnt() {
    if constexpr (N == 2)       asm volatile("s_waitcnt vmcnt(2)"  ::: "memory");
    else if constexpr (N == 3)  asm volatile("s_waitcnt vmcnt(3)"  ::: "memory");
    else if constexpr (N == 6)  asm volatile("s_waitcnt vmcnt(6)"  ::: "memory");
    else if constexpr (N == 8)  asm volatile("s_waitcnt vmcnt(8)"  ::: "memory");
    else                        asm volatile("s_waitcnt vmcnt(0)"  ::: "memory");
}

// ---------------- weight pack: fp32 [K][N] -> bf16 fragment-major ----------
// P[((nt*KC + kc)*64 + lane)*8 + j] = bf16(W[(kc*32 + (lane>>4)*8 + j)*N + nt*16 + (lane&15)])
__global__ __launch_bounds__(256) void pack_w(
    const float* __restrict__ W, unsigned short* __restrict__ P, int K, int N)
{
    const int KC = K >> 5;
    int tile = blockIdx.x * 4 + (threadIdx.x >> 6);
    int lane = threadIdx.x & 63;
    int nt = tile / KC, kc = tile - nt * KC;
    int l16 = lane & 15, quad = lane >> 4;
    const float* src = W + (size_t)(kc * 32 + quad * 8) * N + nt * 16 + l16;
    short8 o;
#pragma unroll
    for (int j = 0; j < 8; ++j) o[j] = (short)f2bf(src[(size_t)j * N]);
    *(short8*)(P + ((size_t)(nt * KC + kc) * 64 + lane) * 8) = o;
}

// ---------------- layernorm fp32 -> bf16 ----------------
__global__ __launch_bounds__(256) void layernorm_bf16(
    const float* __restrict__ X, const float* __restrict__ g,
    const float* __restrict__ b, unsigned short* __restrict__ Y)
{
    int row = blockIdx.x, t = threadIdx.x;
    const float4* xr = (const float4*)(X + (size_t)row * Dd);
    float4 v = xr[t];
    float s  = v.x + v.y + v.z + v.w;
    float s2 = v.x * v.x + v.y * v.y + v.z * v.z + v.w * v.w;
#pragma unroll
    for (int off = 32; off >= 1; off >>= 1) {
        s  += __shfl_down(s, off, 64);
        s2 += __shfl_down(s2, off, 64);
    }
    __shared__ float red[8];
    int wave = t >> 6, lane = t & 63;
    if (lane == 0) { red[wave] = s; red[4 + wave] = s2; }
    __syncthreads();
    float ts  = red[0] + red[1] + red[2] + red[3];
    float ts2 = red[4] + red[5] + red[6] + red[7];
    float mu  = ts * (1.0f / Dd);
    float var = ts2 * (1.0f / Dd) - mu * mu;
    float rstd = rsqrtf(var + 1e-5f);
    float4 gv = ((const float4*)g)[t];
    float4 bv = ((const float4*)b)[t];
    ushort4 o;
    o.x = f2bf((v.x - mu) * rstd * gv.x + bv.x);
    o.y = f2bf((v.y - mu) * rstd * gv.y + bv.y);
    o.z = f2bf((v.z - mu) * rstd * gv.z + bv.z);
    o.w = f2bf((v.w - mu) * rstd * gv.w + bv.w);
    ((ushort4*)(Y + (size_t)row * Dd))[t] = o;
}

// ---------------- gemm3b: 3-buffer BK=32 pipelined GEMM, 2 blocks/CU ------
// MODE 0: out bf16 = A@W + bias
// MODE 1: out fp32 = A@W + bias + res
// MODE 2: out bf16 = gelu_new(A@W + bias)
// WC: waves along N (4 -> BN=256, 2 -> BN=128). 8 waves total, WR=8/WC rows.
template <int MODE, int WC>
__global__ __launch_bounds__(512, 4) void gemm3b(
    const unsigned short* __restrict__ A,   // [M][K] bf16 row-major
    const unsigned short* __restrict__ BP,  // packed weight frags
    const float* __restrict__ bias,
    const float* __restrict__ res,
    void* __restrict__ out,
    int M, int N, int K)
{
    constexpr int NI  = 4;              // B-frags per wave (64 cols)
    constexpr int MI  = WC;             // A-frags per wave (4 or 2)
    constexpr int BN  = WC * 64;        // 256 or 128
    constexpr int LB  = WC / 2;         // B loads/thread/tile (2 or 1)
    constexpr int L   = 1 + LB;         // loads/thread/tile (3 or 2)
    constexpr int ASZ = 128 * 32;       // 8 KB A per buffer (shorts)
    constexpr int BSZ = BN * 32;        // 16/8 KB B per buffer (shorts)
    constexpr int BUF = ASZ + BSZ;
    __shared__ short LD[3 * BUF];       // 72 KB / 48 KB

    const int tid  = threadIdx.x;
    const int wave = tid >> 6, lane = tid & 63;
    const int quad = lane >> 4, l16 = lane & 15;
    const int wrow = wave / WC, wcol = wave % WC;
    const size_t rowA0 = (size_t)blockIdx.x * 128;
    const int NT = K >> 5;              // 32-deep K-tiles (= pack KC)
    const int ntbase = blockIdx.y * (BN >> 4);

    // A staging source: thread -> row rr = tid>>2, chunk slot cc = tid&3;
    // slot cc holds source chunk cc^((rr>>1)&3) (swizzle on global side).
    const int rr = tid >> 2, cc = tid & 3;
    const unsigned short* aSrc = A + (rowA0 + rr) * (size_t)K
                                   + ((cc ^ ((rr >> 1) & 3)) * 8);
    // B staging sources: idx -> local frag nt = idx>>6, element (idx&63)*8.
    const unsigned short* bSrc[LB];
#pragma unroll
    for (int r = 0; r < LB; ++r) {
        int idx = tid + r * 512;
        bSrc[r] = BP + (size_t)(ntbase + (idx >> 6)) * NT * 512 + (idx & 63) * 8;
    }

    floatx4 acc[MI][NI] = {};

    // prologue: stage tiles 0,1 into buffers 0,1; wait tile 0 only.
#pragma unroll
    for (int g = 0; g < 2; ++g) {
        gl2lds16(aSrc + g * 32, LD + g * BUF + tid * 8);
#pragma unroll
        for (int r = 0; r < LB; ++r)
            gl2lds16(bSrc[r] + (size_t)g * 512,
                     LD + g * BUF + ASZ + (tid + r * 512) * 8);
    }
    wait_vmcnt<L>();
    __builtin_amdgcn_s_barrier();

    const int aswz = (l16 >> 1) & 3;
    int buf = 0;
    for (int t = 0; t < NT; ++t) {
        const int ts = (t + 2 < NT) ? t + 2 : NT - 1;   // tail: same bytes
        int sbuf = buf + 2; if (sbuf >= 3) sbuf -= 3;   // (t+2)%3
        const short* Ab = LD + buf * BUF;
        const short* Bt = Ab + ASZ;
        short8 bfr[NI], af[MI];
#pragma unroll
        for (int n = 0; n < NI; ++n)
            bfr[n] = *(const short8*)(Bt + ((wcol * NI + n) * 64 + lane) * 8);
#pragma unroll
        for (int i = 0; i < MI; ++i)
            af[i] = *(const short8*)(Ab + (wrow * (MI * 16) + i * 16 + l16) * 32
                                        + ((quad ^ aswz) * 8));
        // stage tile t+2 (buffer (t+2)%3: not read by t or t+1 -> WAR-safe)
        gl2lds16(aSrc + (size_t)ts * 32, LD + sbuf * BUF + tid * 8);
#pragma unroll
        for (int r = 0; r < LB; ++r)
            gl2lds16(bSrc[r] + (size_t)ts * 512,
                     LD + sbuf * BUF + ASZ + (tid + r * 512) * 8);
        wait_vmcnt<L>();        // tile t+1 landed; t+2 in flight
        __builtin_amdgcn_s_setprio(1);
#pragma unroll
        for (int i = 0; i < MI; ++i)
#pragma unroll
            for (int n = 0; n < NI; ++n)
                acc[i][n] = __builtin_amdgcn_mfma_f32_16x16x32_bf16(
                    af[i], bfr[n], acc[i][n], 0, 0, 0);
        __builtin_amdgcn_s_setprio(0);
        asm volatile("s_barrier" ::: "memory");
        buf = (buf + 1 == 3) ? 0 : buf + 1;
    }

    // epilogue
    const size_t colB = (size_t)blockIdx.y * BN + wcol * 64;
#pragma unroll
    for (int mi = 0; mi < MI; ++mi) {
#pragma unroll
        for (int ni = 0; ni < NI; ++ni) {
            size_t row = rowA0 + wrow * (MI * 16) + mi * 16 + quad * 4;
            size_t col = colB + ni * 16 + l16;
            float bc = bias[col];
#pragma unroll
            for (int r = 0; r < 4; ++r) {
                float v = acc[mi][ni][r] + bc;
                if (MODE == 0) {
                    ((unsigned short*)out)[(row + r) * N + col] = f2bf(v);
                } else if (MODE == 1) {
                    ((float*)out)[(row + r) * N + col] = v + res[(row + r) * N + col];
                } else {
                    float u = 0.7978845608028654f * (v + 0.044715f * v * v * v);
                    float e = __builtin_amdgcn_exp2f(-2.8853900817779268f * u);
                    float gl = v * __builtin_amdgcn_rcpf(1.0f + e);
                    ((unsigned short*)out)[(row + r) * N + col] = f2bf(gl);
                }
            }
        }
    }
}

// ---------------- MFMA flash attention (causal) ----------------
__global__ __launch_bounds__(256, 2) void attn_mfma(
    const unsigned short* __restrict__ qkv,  // [B*S][3072] bf16 q|k|v
    unsigned short* __restrict__ ctx)        // [B*S][1024] bf16
{
    __shared__ unsigned short Ks[64 * 72];
    __shared__ unsigned short VT[64 * 72];
    __shared__ unsigned short PT[128 * 72];

    const int tid  = threadIdx.x;
    const int wave = tid >> 6, lane = tid & 63;
    const int quad = lane >> 4, l16 = lane & 15;
    const int blk = blockIdx.x;
    const int c4 = blk & 3, h = (blk >> 2) & 15, b = blk >> 6;
    const size_t tokbase = (size_t)b * Ss;

    const int skey = tid & 63;
    const int sseg = tid >> 6;

    for (int ci = 0; ci < 2; ++ci) {
        const int chunk = ci ? (7 - c4) : c4;
        const int q0 = chunk * 128;

        short8 qf[2][2];
#pragma unroll
        for (int nb = 0; nb < 2; ++nb)
#pragma unroll
            for (int ks = 0; ks < 2; ++ks) {
                const short8* qp = (const short8*)(qkv
                    + (tokbase + q0 + wave * 32 + nb * 16 + l16) * 3072
                    + h * HD + ks * 32 + quad * 8);
                short8 v = *qp, o;
#pragma unroll
                for (int j = 0; j < 8; ++j)
                    o[j] = (short)f2bf(bf2f((unsigned short)v[j]) * 0.18033688011112042f);
                qf[nb][ks] = o;
            }

        floatx4 Oacc[4][2] = {};
        float mrow[2] = {-3.0e38f, -3.0e38f};
        float lrow[2] = {0.f, 0.f};

        const int nkt = 2 * (chunk + 1);
        for (int kt = 0; kt < nkt; ++kt) {
            __syncthreads();
            {
                const short8* kp = (const short8*)(qkv
                    + (tokbase + kt * 64 + skey) * 3072 + Dd + h * HD + sseg * 16);
                short8 k0 = kp[0], k1 = kp[1];
                *(short8*)(Ks + skey * 72 + sseg * 16)     = k0;
                *(short8*)(Ks + skey * 72 + sseg * 16 + 8) = k1;
                const short8* vp = (const short8*)(qkv
                    + (tokbase + kt * 64 + skey) * 3072 + 2 * Dd + h * HD + sseg * 16);
                short8 v0 = vp[0], v1 = vp[1];
#pragma unroll
                for (int j = 0; j < 8; ++j) {
                    VT[(sseg * 16 + j) * 72 + skey]     = (unsigned short)v0[j];
                    VT[(sseg * 16 + 8 + j) * 72 + skey] = (unsigned short)v1[j];
                }
            }
            __syncthreads();

            floatx4 sacc[4][2] = {};
#pragma unroll
            for (int ks = 0; ks < 2; ++ks) {
                short8 af[4];
#pragma unroll
                for (int mi = 0; mi < 4; ++mi)
                    af[mi] = *(const short8*)(Ks + (mi * 16 + l16) * 72 + ks * 32 + quad * 8);
#pragma unroll
                for (int mi = 0; mi < 4; ++mi)
#pragma unroll
                    for (int nb = 0; nb < 2; ++nb)
                        sacc[mi][nb] = __builtin_amdgcn_mfma_f32_16x16x32_bf16(
                            af[mi], qf[nb][ks], sacc[mi][nb], 0, 0, 0);
            }

            if (kt >= 2 * chunk) {
                const int dk = (kt - 2 * chunk) * 64;
#pragma unroll
                for (int nb = 0; nb < 2; ++nb) {
                    int qrow = wave * 32 + nb * 16 + l16;
#pragma unroll
                    for (int mi = 0; mi < 4; ++mi)
#pragma unroll
                        for (int r = 0; r < 4; ++r)
                            if (dk + mi * 16 + quad * 4 + r > qrow)
                                sacc[mi][nb][r] = -3.0e38f;
                }
            }

#pragma unroll
            for (int nb = 0; nb < 2; ++nb) {
                float mx = sacc[0][nb][0];
#pragma unroll
                for (int mi = 0; mi < 4; ++mi)
#pragma unroll
                    for (int r = 0; r < 4; ++r) mx = fmaxf(mx, sacc[mi][nb][r]);
                mx = fmaxf(mx, __shfl_xor(mx, 16, 64));
                mx = fmaxf(mx, __shfl_xor(mx, 32, 64));
                float mnew  = fmaxf(mrow[nb], mx);
                float alpha = __builtin_amdgcn_exp2f(mrow[nb] - mnew);
                float ls = 0.f;
#pragma unroll
                for (int mi = 0; mi < 4; ++mi) {
                    short4v pk;
#pragma unroll
                    for (int r = 0; r < 4; ++r) {
                        float p = __builtin_amdgcn_exp2f(sacc[mi][nb][r] - mnew);
                        ls += p;
                        pk[r] = (short)f2bf(p);
                    }
                    *(short4v*)(PT + (wave * 32 + nb * 16 + l16) * 72 + mi * 16 + quad * 4) = pk;
                }
                ls += __shfl_xor(ls, 16, 64);
                ls += __shfl_xor(ls, 32, 64);
                lrow[nb] = lrow[nb] * alpha + ls;
                mrow[nb] = mnew;
#pragma unroll
                for (int mi3 = 0; mi3 < 4; ++mi3) Oacc[mi3][nb] *= alpha;
            }
            asm volatile("s_waitcnt lgkmcnt(0)" ::: "memory");

#pragma unroll
            for (int ks2 = 0; ks2 < 2; ++ks2) {
                short8 av[4], bp[2];
#pragma unroll
                for (int mi3 = 0; mi3 < 4; ++mi3)
                    av[mi3] = *(const short8*)(VT + (mi3 * 16 + l16) * 72 + ks2 * 32 + quad * 8);
#pragma unroll
                for (int nb = 0; nb < 2; ++nb)
                    bp[nb] = *(const short8*)(PT + (wave * 32 + nb * 16 + l16) * 72 + ks2 * 32 + quad * 8);
#pragma unroll
                for (int mi3 = 0; mi3 < 4; ++mi3)
#pragma unroll
                    for (int nb = 0; nb < 2; ++nb)
                        Oacc[mi3][nb] = __builtin_amdgcn_mfma_f32_16x16x32_bf16(
                            av[mi3], bp[nb], Oacc[mi3][nb], 0, 0, 0);
            }
        }

#pragma unroll
        for (int nb = 0; nb < 2; ++nb) {
            float inv = 1.0f / lrow[nb];
#pragma unroll
            for (int mi3 = 0; mi3 < 4; ++mi3) {
                short4v ov;
#pragma unroll
                for (int r = 0; r < 4; ++r)
                    ov[r] = (short)f2bf(Oacc[mi3][nb][r] * inv);
                *(short4v*)(PT + (wave * 32 + nb * 16 + l16) * 72 + mi3 * 16 + quad * 4) = ov;
            }
        }
        asm volatile("s_waitcnt lgkmcnt(0)" ::: "memory");
        {
            int ql = lane >> 1, dbase = (lane & 1) * 32;
            unsigned short* op = ctx + (tokbase + q0 + wave * 32 + ql) * Dd + h * HD + dbase;
            const unsigned short* lp = PT + (wave * 32 + ql) * 72 + dbase;
#pragma unroll
            for (int i = 0; i < 4; ++i)
                ((short8*)op)[i] = *(const short8*)(lp + i * 8);
        }
    }
}

// ---------------- launch ----------------
extern "C" void kernel_launch(void* const* d_in, const int* in_sizes, int n_in,
                              void* d_out, int out_size, void* d_ws, size_t ws_size,
                              hipStream_t stream)
{
    const float* x        = (const float*)d_in[0];
    const float* ln1_g    = (const float*)d_in[1];
    const float* ln1_b    = (const float*)d_in[2];
    const float* c_attn_w = (const float*)d_in[3];
    const float* c_attn_b = (const float*)d_in[4];
    const float* c_proj_w = (const float*)d_in[5];
    const float* c_proj_b = (const float*)d_in[6];
    const float* ln2_g    = (const float*)d_in[7];
    const float* ln2_b    = (const float*)d_in[8];
    const float* fc_w     = (const float*)d_in[9];
    const float* fc_b     = (const float*)d_in[10];
    const float* proj_w   = (const float*)d_in[11];
    const float* proj_b   = (const float*)d_in[12];
    float* out = (float*)d_out;

    char* p = (char*)d_ws;
    auto alloc = [&](size_t bytes) {
        void* r = (void*)p;
        p += (bytes + 255) & ~(size_t)255;
        return r;
    };
    unsigned short* WaP  = (unsigned short*)alloc((size_t)3072 * 1024 * 2);
    unsigned short* WpP  = (unsigned short*)alloc((size_t)1024 * 1024 * 2);
    unsigned short* WfP  = (unsigned short*)alloc((size_t)4096 * 1024 * 2);
    unsigned short* Wp2P = (unsigned short*)alloc((size_t)1024 * 4096 * 2);
    unsigned short* h1   = (unsigned short*)alloc((size_t)MTOK * 1024 * 2);
    unsigned short* qkv  = (unsigned short*)alloc((size_t)MTOK * 3072 * 2);
    unsigned short* ctx  = (unsigned short*)alloc((size_t)MTOK * 1024 * 2);
    float*          hmid = (float*)alloc((size_t)MTOK * 1024 * 4);
    unsigned short* h2   = (unsigned short*)alloc((size_t)MTOK * 1024 * 2);
    unsigned short* ff1  = (unsigned short*)alloc((size_t)MTOK * 4096 * 2);

    pack_w<<<(3072 / 16) * (1024 / 32) / 4, 256, 0, stream>>>(c_attn_w, WaP, 1024, 3072);
    pack_w<<<(1024 / 16) * (1024 / 32) / 4, 256, 0, stream>>>(c_proj_w, WpP, 1024, 1024);
    pack_w<<<(4096 / 16) * (1024 / 32) / 4, 256, 0, stream>>>(fc_w, WfP, 1024, 4096);
    pack_w<<<(1024 / 16) * (4096 / 32) / 4, 256, 0, stream>>>(proj_w, Wp2P, 4096, 1024);

    layernorm_bf16<<<MTOK, 256, 0, stream>>>(x, ln1_g, ln1_b, h1);
    // qkv: BN=256, grid 64x12 = 768 blocks (2/CU resident)
    gemm3b<0, 4><<<dim3(64, 12), 512, 0, stream>>>(h1, WaP, c_attn_b, nullptr, qkv, MTOK, 3072, 1024);
    attn_mfma<<<Bb * Hh * 4, 256, 0, stream>>>(qkv, ctx);
    // proj: BN=128, grid 64x8 = 512 blocks (1 full 2/CU round)
    gemm3b<1, 2><<<dim3(64, 8), 512, 0, stream>>>(ctx, WpP, c_proj_b, x, hmid, MTOK, 1024, 1024);
    layernorm_bf16<<<MTOK, 256, 0, stream>>>(hmid, ln2_g, ln2_b, h2);
    // fc: BN=256, grid 64x16 = 1024 blocks (2 full 2/CU rounds)
    gemm3b<2, 4><<<dim3(64, 16), 512, 0, stream>>>(h2, WfP, fc_b, nullptr, ff1, MTOK, 4096, 1024);
    // proj2: BN=128, K=4096, grid 64x8 = 512 blocks (1 full 2/CU round)
    gemm3b<1, 2><<<dim3(64, 8), 512, 0, stream>>>(ff1, Wp2P, proj_b, hmid, out, MTOK, 1024, 4096);
}